// Round 8
// baseline (342.379 us; speedup 1.0000x reference)
//
#include <hip/hip_runtime.h>
#include <hip/hip_bf16.h>

#define H 16
#define DK 64
#define DM 1024
#define LQ 512
#define LK 2048
#define BSZ 4

typedef __hip_bfloat16 bf16;
typedef __attribute__((ext_vector_type(8))) short short8;
typedef __attribute__((ext_vector_type(4))) short short4v;
typedef __attribute__((ext_vector_type(4))) float f32x4;

#define LOG2E 1.44269504f
#define SC2 0.18033688f  // 0.125 * log2(e)

// ---------------- fused converts (SHRUNK): Wq,Wk,Wv,Wo -> bf16; pack bias/mask; btabT ----------------
// q/k/v conversion DELETED: proj_qkv now stages fp32 activations directly and
// converts at fragment-read time (identical __float2bfloat16 rounding).
// pkd: masked entries -> sentinel index 900 (btabT[h][900] = -1e9 -> exp2 -> 0)
// btabT: per-head 901 entries, value = (btab - 10) * log2e  (exp2-domain, shift folded)

__global__ __launch_bounds__(256) void fused_cvt(
    const int* __restrict__ bidx, const int* __restrict__ msk,
    const float* __restrict__ Wq, const float* __restrict__ Wk,
    const float* __restrict__ Wv, const float* __restrict__ Wo,
    const float* __restrict__ btab,
    bf16* __restrict__ Wqb, bf16* __restrict__ Wkb, bf16* __restrict__ Wvb,
    bf16* __restrict__ Wob, short* __restrict__ pkd, float* __restrict__ btabT) {
  const int blk = blockIdx.x, tid = threadIdx.x;
  if (blk < 4096) {
    const float* src;
    bf16* dst;
    const int w = blk >> 10, base = blk & 1023;
    if (w == 0)      { src = Wq; dst = Wqb; }
    else if (w == 1) { src = Wk; dst = Wkb; }
    else if (w == 2) { src = Wv; dst = Wvb; }
    else             { src = Wo; dst = Wob; }
    int i = base * 1024 + tid * 4;
    float4 val = *reinterpret_cast<const float4*>(src + i);
    bf16 o0 = __float2bfloat16(val.x), o1 = __float2bfloat16(val.y);
    bf16 o2 = __float2bfloat16(val.z), o3 = __float2bfloat16(val.w);
    short4 pk;
    pk.x = *reinterpret_cast<short*>(&o0);
    pk.y = *reinterpret_cast<short*>(&o1);
    pk.z = *reinterpret_cast<short*>(&o2);
    pk.w = *reinterpret_cast<short*>(&o3);
    *reinterpret_cast<short4*>(reinterpret_cast<short*>(dst) + i) = pk;
  } else if (blk < 8192) {
    int i = (blk - 4096) * 1024 + tid * 4;
    int4 a = *reinterpret_cast<const int4*>(bidx + i);
    int4 m = *reinterpret_cast<const int4*>(msk + i);
    short4 r;
    r.x = m.x ? (short)a.x : (short)900;
    r.y = m.y ? (short)a.y : (short)900;
    r.z = m.z ? (short)a.z : (short)900;
    r.w = m.w ? (short)a.w : (short)900;
    *reinterpret_cast<short4*>(pkd + i) = r;
  } else {
    // bias table: transpose + fold softmax shift (-10) + log2e, append sentinel
    for (int j = tid; j < H * 901; j += 256) {
      int hh = j / 901, i = j - hh * 901;
      btabT[j] = (i == 900) ? -1e9f : (btab[i * H + hh] - 10.0f) * LOG2E;
    }
  }
}

// ---------------- GEMM body: C[m][n] = sum_k A[m][k]*B[n][k] + bias[n] ----------------
// Single-buffered, 2 barriers per K-step (round-5 proven structure; explicit
// dbuf measured SLOWER in round 7: 69.6 -> 76 us).
// AF32: A (activations) is fp32 in HBM; staged as fp32 via global_load_lds with
// per-row rotate-swizzled SOURCE segments (LDS[r][s] = G[r][(s-r)&7], 8 segs of
// 16B per 128B row) so fragment reads are 2-lanes/seg (conflict-free), then
// converted bf16 at read time — rounding identical to the deleted cvt pass.
// MODE 0: write bf16 head-interleaved  dst[((b*H+h)*Lrows + l)*64 + d]
// MODE 1: d-major V dst[((b*H+h)*64 + d)*LK + key] (computed transposed in-register)
// MODE 2: write f32 row-major          dst[row*N + col]
// TM: 128 (4 waves as 2x2, 64x64 each) or 64 (4 waves as 1x4, 64x32 each)

__device__ __forceinline__ void g2lds16(const void* g, void* l) {
  __builtin_amdgcn_global_load_lds(
      (__attribute__((address_space(1))) void*)(g),
      (__attribute__((address_space(3))) void*)(l), 16, 0, 0);
}

template <int MODE, int TM, bool AF32>
__device__ __forceinline__ void gemm_body(void* __restrict__ AsRaw, bf16* __restrict__ Bs,
                                          const void* __restrict__ A,
                                          const bf16* __restrict__ B,
                                          const float* __restrict__ bias,
                                          void* __restrict__ out,
                                          int M, int N, int K, int Lrows,
                                          int bx, int by) {
  constexpr int NT = (TM == 128) ? 4 : 2;
  const int tid = threadIdx.x;
  const int wave = tid >> 6, lane = tid & 63;
  const int quad = lane >> 4, l15 = lane & 15;
  const int rowbase = (TM == 128) ? (wave >> 1) * 64 : 0;
  const int colbase = (TM == 128) ? (wave & 1) * 64 : wave * 32;
  const int rowA0 = bx * TM, colB0 = by * 128;
  const int srow = lane >> 2, skq = lane & 3;

  f32x4 acc[4][NT];
  const f32x4 zero = {0.f, 0.f, 0.f, 0.f};
  for (int mt = 0; mt < 4; mt++)
    for (int nt = 0; nt < NT; nt++) acc[mt][nt] = zero;

  for (int k0 = 0; k0 < K; k0 += 32) {
    if (AF32) {
      // fp32 A: 128B/row = 8 segs of 16B; rotate-swizzled source
      const float* A32 = (const float*)A;
      float* Ad32 = (float*)AsRaw;
      const int ro = lane >> 3;                    // row-in-group 0..7
      const int gs = ((lane & 7) - ro) & 7;        // global seg to fetch
      for (int c = 0; c < TM / 32; ++c) {
        int rbase = wave * (TM / 4) + c * 8;
        g2lds16(A32 + (size_t)(rowA0 + rbase + ro) * K + k0 + gs * 4,
                Ad32 + rbase * 32);
      }
    } else {
      bf16* Ad = (bf16*)AsRaw;
      if (TM == 128) {
        for (int c = 0; c < 2; ++c) {
          int r = wave * 32 + c * 16;
          g2lds16((const bf16*)A + (size_t)(rowA0 + r + srow) * K + k0 + skq * 8, Ad + r * 32);
        }
      } else {
        int r = wave * 16;
        g2lds16((const bf16*)A + (size_t)(rowA0 + r + srow) * K + k0 + skq * 8, Ad + r * 32);
      }
    }
    for (int c = 0; c < 2; ++c) {
      int r = wave * 32 + c * 16;
      g2lds16(B + (size_t)(colB0 + r + srow) * K + k0 + skq * 8, Bs + r * 32);
    }
    __syncthreads();
    short8 af[4], bfr[NT];
    for (int mt = 0; mt < 4; mt++) {
      const int r = rowbase + mt * 16 + l15;
      if (AF32) {
        const float* Ac32 = (const float*)AsRaw;
        const int s0 = (quad * 2 + l15) & 7, s1 = (quad * 2 + 1 + l15) & 7;
        f32x4 a0 = *reinterpret_cast<const f32x4*>(Ac32 + r * 32 + s0 * 4);
        f32x4 a1 = *reinterpret_cast<const f32x4*>(Ac32 + r * 32 + s1 * 4);
        short8 t;
        for (int j = 0; j < 4; j++) {
          bf16 b0 = __float2bfloat16(a0[j]);
          bf16 b1 = __float2bfloat16(a1[j]);
          t[j] = *reinterpret_cast<short*>(&b0);
          t[4 + j] = *reinterpret_cast<short*>(&b1);
        }
        af[mt] = t;
      } else {
        af[mt] = *reinterpret_cast<const short8*>((const bf16*)AsRaw + r * 32 + quad * 8);
      }
    }
    for (int nt = 0; nt < NT; nt++)
      bfr[nt] = *reinterpret_cast<const short8*>(Bs + (colbase + nt * 16 + l15) * 32 + quad * 8);
    for (int mt = 0; mt < 4; mt++)
      for (int nt = 0; nt < NT; nt++) {
        if (MODE == 1)  // swapped: A-op = W rows (n), B-op = act rows (m=key)
          acc[mt][nt] = __builtin_amdgcn_mfma_f32_16x16x32_bf16(bfr[nt], af[mt], acc[mt][nt], 0, 0, 0);
        else
          acc[mt][nt] = __builtin_amdgcn_mfma_f32_16x16x32_bf16(af[mt], bfr[nt], acc[mt][nt], 0, 0, 0);
      }
    __syncthreads();
  }

  const int bb = (MODE == 2) ? 0 : (rowA0 / Lrows);
  const int lb = (MODE == 2) ? rowA0 : (rowA0 - bb * Lrows);
  if (MODE == 1) {
    // D[row=quad*4+r -> n(d-col)][col=l15 -> m(key)]
    for (int mt = 0; mt < 4; mt++) {
      int key = lb + rowbase + mt * 16 + l15;
      for (int nt = 0; nt < NT; nt++) {
        f32x4 v = acc[mt][nt];
        for (int r = 0; r < 4; r++) {
          int ncol = colB0 + colbase + nt * 16 + quad * 4 + r;
          float bv = bias[ncol];
          int hh = ncol >> 6, d = ncol & 63;
          ((bf16*)out)[((size_t)((bb * H + hh) * DK + d)) * LK + key] =
              __float2bfloat16(v[r] + bv);
        }
      }
    }
    return;
  }
  for (int nt = 0; nt < NT; nt++) {
    int col = colB0 + colbase + nt * 16 + l15;
    float bv = bias[col];
    int hh = col >> 6, d = col & 63;
    for (int mt = 0; mt < 4; mt++) {
      int lrow0 = lb + rowbase + mt * 16 + quad * 4;
      f32x4 v = acc[mt][nt];
      for (int r = 0; r < 4; r++) {
        float val = v[r] + bv;
        if (MODE == 0) {
          ((bf16*)out)[(((size_t)(bb * H + hh) * Lrows + lrow0 + r) << 6) + d] = __float2bfloat16(val);
        } else {
          ((float*)out)[(size_t)(lrow0 + r) * N + col] = val;
        }
      }
    }
  }
}

// Merged Q/K/V projection reading fp32 activations directly (cvt folded in).
// One launch, 1280 blocks (K:512, V:512, Q:256). XCD-chunked remap: xcd = blk&7
// owns a contiguous bx-range with ALL by values (A-panels single-XCD).
// LDS: A fp32 16KB + B bf16 8KB = 24KB -> 6 blocks/CU.
__global__ __launch_bounds__(256) void proj_qkv(
    const float* __restrict__ k, const bf16* __restrict__ Wkb, const float* __restrict__ bk, bf16* __restrict__ Kh,
    const float* __restrict__ v, const bf16* __restrict__ Wvb, const float* __restrict__ bv, bf16* __restrict__ Vt,
    const float* __restrict__ q, const bf16* __restrict__ Wqb, const float* __restrict__ bq, bf16* __restrict__ Qh) {
  __shared__ __align__(16) char AsRaw[128 * 32 * 4];
  __shared__ __align__(16) bf16 Bs[128 * 32];
  const int blk = blockIdx.x;
  if (blk < 512) {
    const int xcd = blk & 7, slot = blk >> 3;
    gemm_body<0, 128, true>(AsRaw, Bs, k, Wkb, bk, (void*)Kh, 8192, 1024, 1024, LK,
                            xcd * 8 + (slot & 7), slot >> 3);
  } else if (blk < 1024) {
    const int i = blk - 512, xcd = i & 7, slot = i >> 3;
    gemm_body<1, 128, true>(AsRaw, Bs, v, Wvb, bv, (void*)Vt, 8192, 1024, 1024, LK,
                            xcd * 8 + (slot & 7), slot >> 3);
  } else {
    const int i = blk - 1024, xcd = i & 7, slot = i >> 3;
    gemm_body<0, 64, true>(AsRaw, Bs, q, Wqb, bq, (void*)Qh, 2048, 1024, 1024, LQ,
                           xcd * 4 + (slot & 3), slot >> 2);
  }
}

// Output projection (A = Ob bf16, unchanged path). 1-D grid of 256 blocks:
// xcd = blk&7 owns 4 bx rows x all 8 by columns (bijective over 256).
__global__ __launch_bounds__(256) void gemm_o(const bf16* __restrict__ A,
                                              const bf16* __restrict__ B,
                                              const float* __restrict__ bias,
                                              float* __restrict__ out) {
  __shared__ __align__(16) char AsRaw[64 * 32 * 2];
  __shared__ __align__(16) bf16 Bs[128 * 32];
  const int blk = blockIdx.x, xcd = blk & 7, slot = blk >> 3;
  gemm_body<2, 64, false>(AsRaw, Bs, A, B, bias, (void*)out, 2048, 1024, 1024, LQ,
                          xcd * 4 + (slot & 3), slot >> 2);
}

// ---------------- attention v9: 8-wave blocks (128 q rows), dbuf, 1 barrier/chunk ----------------
// grid (BSZ*H, LQ/128, 2), block 512. Block = (bh, 128 q rows, 1024 keys, 16 chunks).

__global__ __launch_bounds__(512) void attn9(const bf16* __restrict__ Qh,
                                             const bf16* __restrict__ Kh,
                                             const bf16* __restrict__ Vt,
                                             const short* __restrict__ pkm,
                                             const float* __restrict__ btabT,
                                             float* __restrict__ Opart,
                                             float* __restrict__ L) {
  __shared__ __align__(16) bf16 Kbuf[2][64 * 64];
  __shared__ __align__(16) bf16 Vbuf[2][64 * 64];
  __shared__ float bts[901];
  const int tid = threadIdx.x;
  const int wave = tid >> 6, lane = tid & 63;
  const int quad = lane >> 4, l15 = lane & 15;
  const int bh = blockIdx.x, b = bh >> 4, h = bh & 15;
  const int qt = blockIdx.y, z = blockIdx.z;
  const int key_base = z * 1024;

  for (int i = tid; i < 901; i += 512) bts[i] = btabT[h * 901 + i];

  const int q = qt * 128 + wave * 16 + l15;  // this lane's q (B-operand col)
  short8 qf[2];
  for (int ks = 0; ks < 2; ks++)
    qf[ks] = *reinterpret_cast<const short8*>(
        Qh + ((size_t)bh * LQ + q) * DK + ks * 32 + quad * 8);

  const bf16* kbase = Kh + ((size_t)bh * LK + key_base) * DK;
  const bf16* vbase = Vt + ((size_t)bh * DK) * LK + key_base;
  const short* pkrow = pkm + ((size_t)b * LQ + q) * LK + key_base;

  // staging geometry (per wave, 1 inst each for K and V):
  // lane i -> LDS row wave*8 + (i>>3), seg i&7 (lane-linear DMA);
  // row's global seg g = ((i&7) - (i>>3)) & 7   (rotate swizzle, row%8 = i>>3)
  const int srow_off = lane >> 3;                // 0..7
  const int sseg = ((lane & 7) - srow_off) & 7;  // global segment to fetch
  const int srow = wave * 8 + srow_off;          // this lane's staged row

  f32x4 of[4];
  float denom = 0.f;
  const f32x4 zero = {0.f, 0.f, 0.f, 0.f};
  for (int dt = 0; dt < 4; dt++) of[dt] = zero;

  // ---- prologue: stage chunk 0 into buf0, prefetch pk chunk 0 ----
  g2lds16(kbase + (size_t)srow * DK + sseg * 8, &Kbuf[0][(wave * 8) * 64]);
  g2lds16(vbase + (size_t)srow * LK + sseg * 8, &Vbuf[0][(wave * 8) * 64]);
  short4v pkv[4];
  for (int nt = 0; nt < 4; nt++)
    pkv[nt] = *reinterpret_cast<const short4v*>(pkrow + nt * 16 + quad * 4);

  __syncthreads();

  for (int kc = 0; kc < 16; ++kc) {
    const int buf = kc & 1;

    // stage chunk kc+1 into buf^1 (completes at the end-of-iter barrier)
    short4v pk_n[4];
    if (kc < 15) {
      const int key1 = (kc + 1) * 64;
      g2lds16(kbase + (size_t)(key1 + srow) * DK + sseg * 8,
              &Kbuf[buf ^ 1][(wave * 8) * 64]);
      g2lds16(vbase + (size_t)srow * LK + key1 + sseg * 8,
              &Vbuf[buf ^ 1][(wave * 8) * 64]);
      for (int nt = 0; nt < 4; nt++)
        pk_n[nt] = *reinterpret_cast<const short4v*>(pkrow + key1 + nt * 16 + quad * 4);
    }

    // K frags from LDS (swizzled): row = nt*16+l15, global seg ks*4+quad
    // at LDS seg (ks*4+quad+l15)&7
    f32x4 sa[4];
    for (int nt = 0; nt < 4; nt++) sa[nt] = zero;
    for (int nt = 0; nt < 4; nt++)
      for (int ks = 0; ks < 2; ks++) {
        short8 kf = *reinterpret_cast<const short8*>(
            &Kbuf[buf][(nt * 16 + l15) * 64 + (((ks * 4 + quad + l15) & 7) << 3)]);
        sa[nt] = __builtin_amdgcn_mfma_f32_16x16x32_bf16(kf, qf[ks], sa[nt], 0, 0, 0);
      }

    // V frags from LDS (swizzled): row d = dt*16+l15, global seg nt*2+(quad>>1),
    // sub-offset (quad&1)*4 elems -> LDS seg (nt*2+(quad>>1)+l15)&7
    short4v vf[4][4];
    for (int dt = 0; dt < 4; dt++)
      for (int nt = 0; nt < 4; nt++)
        vf[dt][nt] = *reinterpret_cast<const short4v*>(
            &Vbuf[buf][(dt * 16 + l15) * 64 +
                       (((nt * 2 + (quad >> 1) + l15) & 7) << 3) + ((quad & 1) << 2)]);

    // p = exp2(s * 0.125*log2e + bts[idx])  (masked idx=900 -> -1e9 -> 0)
    short4v pf[4];
    for (int nt = 0; nt < 4; nt++) {
      float p[4];
      for (int r = 0; r < 4; r++) {
        float t = fmaf(sa[nt][r], SC2, bts[pkv[nt][r]]);
        p[r] = __builtin_amdgcn_exp2f(t);
      }
      denom += (p[0] + p[1]) + (p[2] + p[3]);
      short4v pk4;
      for (int r = 0; r < 4; r++) {
        bf16 tb = __float2bfloat16(p[r]);
        pk4[r] = *reinterpret_cast<short*>(&tb);
      }
      pf[nt] = pk4;
    }

    // PV: O^T[d][q] += V[d][key] * P^T[key][q]
    for (int dt = 0; dt < 4; dt++)
      for (int nt = 0; nt < 4; nt++)
        of[dt] = __builtin_amdgcn_mfma_f32_16x16x16bf16_1k(vf[dt][nt], pf[nt], of[dt], 0, 0, 0);

    if (kc < 15)
      for (int nt = 0; nt < 4; nt++) pkv[nt] = pk_n[nt];

    __syncthreads();  // staging of buf^1 complete; all reads of buf done
  }

  // cross-quad reduction of the denominator (keys split across quads)
  denom += __shfl_xor(denom, 16, 64);
  denom += __shfl_xor(denom, 32, 64);

  size_t rowi = ((size_t)z * 64 + bh) * LQ + q;
  float* orow = Opart + rowi * 64;
  for (int dt = 0; dt < 4; dt++)
    *reinterpret_cast<f32x4*>(orow + dt * 16 + quad * 4) = of[dt];
  if (quad == 0) L[rowi] = denom;
}

// combine the two split-K halves -> bf16 Ob (plain sums; same fixed shift)
__global__ __launch_bounds__(256) void attn_combine(const float* __restrict__ Opart,
                                                    const float* __restrict__ L,
                                                    bf16* __restrict__ Ob) {
  int t = blockIdx.x * 256 + threadIdx.x;  // over 2M/4
  int g = t * 4;
  int row = g >> 6, d0 = g & 63;
  float l = L[row] + L[32768 + row];
  float4 o;
  float4 p0 = *reinterpret_cast<const float4*>(Opart + ((size_t)row << 6) + d0);
  float4 p1 = *reinterpret_cast<const float4*>(Opart + (((size_t)32768 + row) << 6) + d0);
  o.x = p0.x + p1.x; o.y = p0.y + p1.y; o.z = p0.z + p1.z; o.w = p0.w + p1.w;
  float inv = 1.f / l;
  bf16 t0 = __float2bfloat16(o.x * inv), t1 = __float2bfloat16(o.y * inv);
  bf16 t2 = __float2bfloat16(o.z * inv), t3 = __float2bfloat16(o.w * inv);
  short4 pk;
  pk.x = *reinterpret_cast<short*>(&t0);
  pk.y = *reinterpret_cast<short*>(&t1);
  pk.z = *reinterpret_cast<short*>(&t2);
  pk.w = *reinterpret_cast<short*>(&t3);
  int bh = row >> 9, qq = row & 511, b_ = bh >> 4, h = bh & 15;
  *reinterpret_cast<short4*>(Ob + ((size_t)(b_ * LQ + qq)) * DM + h * 64 + d0) = pk;
}

// ---------------- launcher ----------------

extern "C" void kernel_launch(void* const* d_in, const int* in_sizes, int n_in,
                              void* d_out, int out_size, void* d_ws, size_t ws_size,
                              hipStream_t stream) {
  const float* q = (const float*)d_in[0];
  const float* k = (const float*)d_in[1];
  const float* v = (const float*)d_in[2];
  const int* bidx = (const int*)d_in[3];
  const int* mask = (const int*)d_in[4];
  const float* Wq = (const float*)d_in[5];
  const float* bq = (const float*)d_in[6];
  const float* Wk = (const float*)d_in[7];
  const float* bk = (const float*)d_in[8];
  const float* Wv = (const float*)d_in[9];
  const float* bv = (const float*)d_in[10];
  const float* Wo = (const float*)d_in[11];
  const float* bo = (const float*)d_in[12];
  const float* btab = (const float*)d_in[13];

  char* ws = (char*)d_ws;
  bf16* Wqb = (bf16*)(ws + 37748736);
  bf16* Wkb = (bf16*)(ws + 39845888);
  bf16* Wvb = (bf16*)(ws + 41943040);
  bf16* Wob = (bf16*)(ws + 44040192);
  bf16* Qh  = (bf16*)(ws + 46137344);
  bf16* Kh  = (bf16*)(ws + 50331648);
  bf16* Vt  = (bf16*)(ws + 67108864);
  short* pkd = (short*)(ws + 83886080);
  bf16* Ob  = (bf16*)(ws + 92274688);
  // btabT overlays the START of the Ob region: written by fused_cvt, read by
  // attn9, and only THEN overwritten by attn_combine (stream-ordered — safe).
  float* btabT = (float*)(ws + 92274688);      // 57,664 B
  // Opart/L live in the (now unused) former qb/kb region
  float* Opart = (float*)(ws + 0);             // 16,777,216 B (2 z-halves)
  float* L     = (float*)(ws + 16777216);      //    262,144 B
  (void)ws_size; (void)in_sizes; (void)n_in; (void)out_size;

  hipLaunchKernelGGL(fused_cvt, dim3(8193), dim3(256), 0, stream,
                     bidx, mask, Wq, Wk, Wv, Wo, btab,
                     Wqb, Wkb, Wvb, Wob, pkd, btabT);

  hipLaunchKernelGGL(proj_qkv, dim3(1280), dim3(256), 0, stream,
                     k, Wkb, bk, Kh, v, Wvb, bv, Vt, q, Wqb, bq, Qh);

  hipLaunchKernelGGL(attn9, dim3(BSZ * H, LQ / 128, 2), dim3(512), 0, stream,
                     Qh, Kh, Vt, pkd, btabT, Opart, L);
  hipLaunchKernelGGL(attn_combine, dim3(2048), dim3(256), 0, stream,
                     Opart, L, Ob);

  hipLaunchKernelGGL(gemm_o, dim3(256), dim3(256), 0, stream,
                     Ob, Wob, bo, (float*)d_out);
}

// Round 10
// 318.226 us; speedup vs baseline: 1.0759x; 1.0759x over previous
//
#include <hip/hip_runtime.h>
#include <hip/hip_bf16.h>

#define H 16
#define DK 64
#define DM 1024
#define LQ 512
#define LK 2048
#define BSZ 4

typedef __hip_bfloat16 bf16;
typedef __attribute__((ext_vector_type(8))) short short8;
typedef __attribute__((ext_vector_type(4))) short short4v;
typedef __attribute__((ext_vector_type(4))) float f32x4;

#define LOG2E 1.44269504f
#define SC2 0.18033688f  // 0.125 * log2(e)

// ---------------- fused converts: q,k,v,Wq,Wk,Wv,Wo -> bf16; pack bias/mask; btabT ----------------
// ILP layout (FIXED round 10): each block owns 1024 float4 (16KB); 256 threads
// x 4 independent float4 loads each. (Round-9 bug: block stride was 4096 but
// threads only covered 1024 -> 3/4 of the data never converted.)
// pkd: masked entries -> sentinel index 900 (btabT[h][900] = -1e9 -> exp2 -> 0)
// btabT: per-head 901 entries, value = (btab - 10) * log2e  (exp2-domain, shift folded)

__device__ __forceinline__ short4 cvt4(float4 v) {
  bf16 o0 = __float2bfloat16(v.x), o1 = __float2bfloat16(v.y);
  bf16 o2 = __float2bfloat16(v.z), o3 = __float2bfloat16(v.w);
  short4 pk;
  pk.x = *reinterpret_cast<short*>(&o0);
  pk.y = *reinterpret_cast<short*>(&o1);
  pk.z = *reinterpret_cast<short*>(&o2);
  pk.w = *reinterpret_cast<short*>(&o3);
  return pk;
}

__global__ __launch_bounds__(256) void fused_cvt(
    const float* __restrict__ q, const float* __restrict__ k, const float* __restrict__ v,
    const int* __restrict__ bidx, const int* __restrict__ msk,
    const float* __restrict__ Wq, const float* __restrict__ Wk,
    const float* __restrict__ Wv, const float* __restrict__ Wo,
    const float* __restrict__ btab,
    bf16* __restrict__ qb, bf16* __restrict__ kb, bf16* __restrict__ vb,
    bf16* __restrict__ Wqb, bf16* __restrict__ Wkb, bf16* __restrict__ Wvb,
    bf16* __restrict__ Wob, short* __restrict__ pkd, float* __restrict__ btabT) {
  const int blk = blockIdx.x, tid = threadIdx.x;
  if (blk < 5632) {
    // activation / weight conversion: block = 1024 float4 (16KB fp32 -> 8KB bf16)
    const float* src;
    bf16* dst;
    int base;
    if (blk < 512)       { src = q;  dst = qb;  base = blk; }
    else if (blk < 2560) { src = k;  dst = kb;  base = blk - 512; }
    else if (blk < 4608) { src = v;  dst = vb;  base = blk - 2560; }
    else {
      const int wi = blk - 4608, w = wi >> 8;
      base = wi & 255;
      src = (w == 0) ? Wq : (w == 1) ? Wk : (w == 2) ? Wv : Wo;
      dst = (w == 0) ? Wqb : (w == 1) ? Wkb : (w == 2) ? Wvb : Wob;
    }
    const float4* s = reinterpret_cast<const float4*>(src) + (size_t)base * 1024 + tid;
    short4* d = reinterpret_cast<short4*>(dst) + (size_t)base * 1024 + tid;
    float4 v0 = s[0], v1 = s[256], v2 = s[512], v3 = s[768];  // 4 indep loads
    d[0] = cvt4(v0);
    d[256] = cvt4(v1);
    d[512] = cvt4(v2);
    d[768] = cvt4(v3);
  } else if (blk < 6656) {
    // bias-index/mask pack: block = 1024 int4 pairs -> 1024 short4
    const int base = blk - 5632;
    const int4* sa = reinterpret_cast<const int4*>(bidx) + (size_t)base * 1024 + tid;
    const int4* sm = reinterpret_cast<const int4*>(msk) + (size_t)base * 1024 + tid;
    short4* d = reinterpret_cast<short4*>(pkd) + (size_t)base * 1024 + tid;
#pragma unroll
    for (int it = 0; it < 4; ++it) {
      int4 a = sa[it * 256];
      int4 m = sm[it * 256];
      short4 r;
      r.x = m.x ? (short)a.x : (short)900;
      r.y = m.y ? (short)a.y : (short)900;
      r.z = m.z ? (short)a.z : (short)900;
      r.w = m.w ? (short)a.w : (short)900;
      d[it * 256] = r;
    }
  } else {
    // bias table: transpose + fold softmax shift (-10) + log2e, append sentinel
    for (int j = tid; j < H * 901; j += 256) {
      int hh = j / 901, i = j - hh * 901;
      btabT[j] = (i == 900) ? -1e9f : (btab[i * H + hh] - 10.0f) * LOG2E;
    }
  }
}

// ---------------- GEMM body: C[m][n] = sum_k A[m][k]*B[n][k] + bias[n] ----------------
// Single-buffered, 2 barriers per K-step (round-5 proven structure; explicit
// dbuf and fp32-direct staging both measured SLOWER — rounds 7/8).
// MODE 0: write bf16 head-interleaved  dst[((b*H+h)*Lrows + l)*64 + d]
// MODE 1: d-major V dst[((b*H+h)*64 + d)*LK + key] (computed transposed in-register)
// MODE 2: write f32 row-major          dst[row*N + col]
// MODE 3: like MODE 2, but A is produced ON THE FLY from the split-K attention
//         partials: A[row][c] = (Opart[z0]+Opart[z1]) * 1/(L[z0]+L[z1]) cvt bf16
//         (bit-identical to the deleted attn_combine pass; fragment/MFMA path
//         untouched — staging is reg-mediated ds_write into the same layout).
// TM: 128 (4 waves as 2x2, 64x64 each) or 64 (4 waves as 1x4, 64x32 each)

__device__ __forceinline__ void g2lds16(const void* g, void* l) {
  __builtin_amdgcn_global_load_lds(
      (__attribute__((address_space(1))) void*)(g),
      (__attribute__((address_space(3))) void*)(l), 16, 0, 0);
}

template <int MODE, int TM>
__device__ __forceinline__ void gemm_body(bf16* __restrict__ As, bf16* __restrict__ Bs,
                                          const void* __restrict__ A,
                                          const bf16* __restrict__ B,
                                          const float* __restrict__ bias,
                                          const float* __restrict__ Lp,
                                          void* __restrict__ out,
                                          int M, int N, int K, int Lrows,
                                          int bx, int by) {
  constexpr int NT = (TM == 128) ? 4 : 2;
  const int tid = threadIdx.x;
  const int wave = tid >> 6, lane = tid & 63;
  const int quad = lane >> 4, l15 = lane & 15;
  const int rowbase = (TM == 128) ? (wave >> 1) * 64 : 0;
  const int colbase = (TM == 128) ? (wave & 1) * 64 : wave * 32;
  const int rowA0 = bx * TM, colB0 = by * 128;
  const int srow = lane >> 2, skq = lane & 3;

  f32x4 acc[4][NT];
  const f32x4 zero = {0.f, 0.f, 0.f, 0.f};
  for (int mt = 0; mt < 4; mt++)
    for (int nt = 0; nt < NT; nt++) acc[mt][nt] = zero;

  for (int k0 = 0; k0 < K; k0 += 32) {
    if (MODE == 3) {
      // fused combine: build A tile in registers from Opart/L, write to LDS
      const float* Op = (const float*)A;
      const int r = wave * 16 + srow;      // 0..63
      const int row = rowA0 + r;           // O row = b*512+qq
      const int b_ = row >> 9, qq = row & 511;
      const int c0 = k0 + skq * 8;         // 8 cols, within one head
      const int h = c0 >> 6, d0 = c0 & 63;
      const size_t ri = (size_t)(b_ * 16 + h) * 512 + qq;
      const float inv = 1.f / (Lp[ri] + Lp[32768 + ri]);
      const float* p0 = Op + ri * 64 + d0;
      const float* p1 = Op + (size_t)(32768 + ri) * 64 + d0;
      f32x4 a0 = *reinterpret_cast<const f32x4*>(p0);
      f32x4 a1 = *reinterpret_cast<const f32x4*>(p0 + 4);
      f32x4 b0 = *reinterpret_cast<const f32x4*>(p1);
      f32x4 b1 = *reinterpret_cast<const f32x4*>(p1 + 4);
      short8 wv;
      for (int j = 0; j < 4; j++) {
        bf16 x = __float2bfloat16((a0[j] + b0[j]) * inv);
        bf16 y = __float2bfloat16((a1[j] + b1[j]) * inv);
        wv[j] = *reinterpret_cast<short*>(&x);
        wv[4 + j] = *reinterpret_cast<short*>(&y);
      }
      *reinterpret_cast<short8*>(As + r * 32 + skq * 8) = wv;
    } else if (TM == 128) {
      for (int c = 0; c < 2; ++c) {
        int r = wave * 32 + c * 16;
        g2lds16((const bf16*)A + (size_t)(rowA0 + r + srow) * K + k0 + skq * 8, As + r * 32);
      }
    } else {
      int r = wave * 16;
      g2lds16((const bf16*)A + (size_t)(rowA0 + r + srow) * K + k0 + skq * 8, As + r * 32);
    }
    for (int c = 0; c < 2; ++c) {
      int r = wave * 32 + c * 16;
      g2lds16(B + (size_t)(colB0 + r + srow) * K + k0 + skq * 8, Bs + r * 32);
    }
    __syncthreads();
    short8 af[4], bfr[NT];
    for (int mt = 0; mt < 4; mt++)
      af[mt] = *reinterpret_cast<const short8*>(As + (rowbase + mt * 16 + l15) * 32 + quad * 8);
    for (int nt = 0; nt < NT; nt++)
      bfr[nt] = *reinterpret_cast<const short8*>(Bs + (colbase + nt * 16 + l15) * 32 + quad * 8);
    for (int mt = 0; mt < 4; mt++)
      for (int nt = 0; nt < NT; nt++) {
        if (MODE == 1)  // swapped: A-op = W rows (n), B-op = act rows (m=key)
          acc[mt][nt] = __builtin_amdgcn_mfma_f32_16x16x32_bf16(bfr[nt], af[mt], acc[mt][nt], 0, 0, 0);
        else
          acc[mt][nt] = __builtin_amdgcn_mfma_f32_16x16x32_bf16(af[mt], bfr[nt], acc[mt][nt], 0, 0, 0);
      }
    __syncthreads();
  }

  const int bb = (MODE >= 2) ? 0 : (rowA0 / Lrows);
  const int lb = (MODE >= 2) ? rowA0 : (rowA0 - bb * Lrows);
  if (MODE == 1) {
    // D[row=quad*4+r -> n(d-col)][col=l15 -> m(key)]
    for (int mt = 0; mt < 4; mt++) {
      int key = lb + rowbase + mt * 16 + l15;
      for (int nt = 0; nt < NT; nt++) {
        f32x4 v = acc[mt][nt];
        for (int r = 0; r < 4; r++) {
          int ncol = colB0 + colbase + nt * 16 + quad * 4 + r;
          float bv = bias[ncol];
          int hh = ncol >> 6, d = ncol & 63;
          ((bf16*)out)[((size_t)((bb * H + hh) * DK + d)) * LK + key] =
              __float2bfloat16(v[r] + bv);
        }
      }
    }
    return;
  }
  for (int nt = 0; nt < NT; nt++) {
    int col = colB0 + colbase + nt * 16 + l15;
    float bv = bias[col];
    int hh = col >> 6, d = col & 63;
    for (int mt = 0; mt < 4; mt++) {
      int lrow0 = lb + rowbase + mt * 16 + quad * 4;
      f32x4 v = acc[mt][nt];
      for (int r = 0; r < 4; r++) {
        float val = v[r] + bv;
        if (MODE == 0) {
          ((bf16*)out)[(((size_t)(bb * H + hh) * Lrows + lrow0 + r) << 6) + d] = __float2bfloat16(val);
        } else {
          ((float*)out)[(size_t)(lrow0 + r) * N + col] = val;
        }
      }
    }
  }
}

// Merged Q/K/V projection: one launch, 1280 blocks (K:512, V:512, Q:256).
// XCD-chunked remap: xcd = blk&7 (HW round-robin) owns a contiguous bx-range
// with ALL by values, so each A-activation panel is fetched by exactly ONE
// XCD's L2. (round-5 proven configuration)
__global__ __launch_bounds__(256) void proj_qkv(
    const bf16* __restrict__ kb, const bf16* __restrict__ Wkb, const float* __restrict__ bk, bf16* __restrict__ Kh,
    const bf16* __restrict__ vb, const bf16* __restrict__ Wvb, const float* __restrict__ bv, bf16* __restrict__ Vt,
    const bf16* __restrict__ qb, const bf16* __restrict__ Wqb, const float* __restrict__ bq, bf16* __restrict__ Qh) {
  __shared__ __align__(16) bf16 As[128 * 32];
  __shared__ __align__(16) bf16 Bs[128 * 32];
  const int blk = blockIdx.x;
  if (blk < 512) {
    const int xcd = blk & 7, slot = blk >> 3;
    gemm_body<0, 128>(As, Bs, kb, Wkb, bk, nullptr, (void*)Kh, 8192, 1024, 1024, LK,
                      xcd * 8 + (slot & 7), slot >> 3);
  } else if (blk < 1024) {
    const int i = blk - 512, xcd = i & 7, slot = i >> 3;
    gemm_body<1, 128>(As, Bs, vb, Wvb, bv, nullptr, (void*)Vt, 8192, 1024, 1024, LK,
                      xcd * 8 + (slot & 7), slot >> 3);
  } else {
    const int i = blk - 1024, xcd = i & 7, slot = i >> 3;
    gemm_body<0, 64>(As, Bs, qb, Wqb, bq, nullptr, (void*)Qh, 2048, 1024, 1024, LQ,
                     xcd * 4 + (slot & 3), slot >> 2);
  }
}

// Output projection with FUSED split-K combine (attn_combine kernel deleted).
// A operand = Opart/L; staging computes (p0+p1)/l and writes bf16 LDS tiles.
// 1-D grid of 256 blocks: xcd = blk&7 owns 4 bx rows x all 8 by cols.
__global__ __launch_bounds__(256) void gemm_o(const float* __restrict__ Opart,
                                              const bf16* __restrict__ B,
                                              const float* __restrict__ bias,
                                              const float* __restrict__ Lp,
                                              float* __restrict__ out) {
  __shared__ __align__(16) bf16 As[64 * 32];
  __shared__ __align__(16) bf16 Bs[128 * 32];
  const int blk = blockIdx.x, xcd = blk & 7, slot = blk >> 3;
  gemm_body<3, 64>(As, Bs, Opart, B, bias, Lp, (void*)out, 2048, 1024, 1024, LQ,
                   xcd * 4 + (slot & 3), slot >> 2);
}

// ---------------- attention v9: 8-wave blocks (128 q rows), dbuf, 1 barrier/chunk ----------------
// (round-5 proven configuration — counted-vmcnt and other schedule tweaks
// measured null/negative in rounds 6-8)
// grid (BSZ*H, LQ/128, 2), block 512. Block = (bh, 128 q rows, 1024 keys, 16 chunks).

__global__ __launch_bounds__(512) void attn9(const bf16* __restrict__ Qh,
                                             const bf16* __restrict__ Kh,
                                             const bf16* __restrict__ Vt,
                                             const short* __restrict__ pkm,
                                             const float* __restrict__ btabT,
                                             float* __restrict__ Opart,
                                             float* __restrict__ L) {
  __shared__ __align__(16) bf16 Kbuf[2][64 * 64];
  __shared__ __align__(16) bf16 Vbuf[2][64 * 64];
  __shared__ float bts[901];
  const int tid = threadIdx.x;
  const int wave = tid >> 6, lane = tid & 63;
  const int quad = lane >> 4, l15 = lane & 15;
  const int bh = blockIdx.x, b = bh >> 4, h = bh & 15;
  const int qt = blockIdx.y, z = blockIdx.z;
  const int key_base = z * 1024;

  for (int i = tid; i < 901; i += 512) bts[i] = btabT[h * 901 + i];

  const int q = qt * 128 + wave * 16 + l15;  // this lane's q (B-operand col)
  short8 qf[2];
  for (int ks = 0; ks < 2; ks++)
    qf[ks] = *reinterpret_cast<const short8*>(
        Qh + ((size_t)bh * LQ + q) * DK + ks * 32 + quad * 8);

  const bf16* kbase = Kh + ((size_t)bh * LK + key_base) * DK;
  const bf16* vbase = Vt + ((size_t)bh * DK) * LK + key_base;
  const short* pkrow = pkm + ((size_t)b * LQ + q) * LK + key_base;

  // staging geometry (per wave, 1 inst each for K and V):
  // lane i -> LDS row wave*8 + (i>>3), seg i&7 (lane-linear DMA);
  // row's global seg g = ((i&7) - (i>>3)) & 7   (rotate swizzle, row%8 = i>>3)
  const int srow_off = lane >> 3;                // 0..7
  const int sseg = ((lane & 7) - srow_off) & 7;  // global segment to fetch
  const int srow = wave * 8 + srow_off;          // this lane's staged row

  f32x4 of[4];
  float denom = 0.f;
  const f32x4 zero = {0.f, 0.f, 0.f, 0.f};
  for (int dt = 0; dt < 4; dt++) of[dt] = zero;

  // ---- prologue: stage chunk 0 into buf0, prefetch pk chunk 0 ----
  g2lds16(kbase + (size_t)srow * DK + sseg * 8, &Kbuf[0][(wave * 8) * 64]);
  g2lds16(vbase + (size_t)srow * LK + sseg * 8, &Vbuf[0][(wave * 8) * 64]);
  short4v pkv[4];
  for (int nt = 0; nt < 4; nt++)
    pkv[nt] = *reinterpret_cast<const short4v*>(pkrow + nt * 16 + quad * 4);

  __syncthreads();

  for (int kc = 0; kc < 16; ++kc) {
    const int buf = kc & 1;

    // stage chunk kc+1 into buf^1 (completes at the end-of-iter barrier)
    short4v pk_n[4];
    if (kc < 15) {
      const int key1 = (kc + 1) * 64;
      g2lds16(kbase + (size_t)(key1 + srow) * DK + sseg * 8,
              &Kbuf[buf ^ 1][(wave * 8) * 64]);
      g2lds16(vbase + (size_t)srow * LK + key1 + sseg * 8,
              &Vbuf[buf ^ 1][(wave * 8) * 64]);
      for (int nt = 0; nt < 4; nt++)
        pk_n[nt] = *reinterpret_cast<const short4v*>(pkrow + key1 + nt * 16 + quad * 4);
    }

    // K frags from LDS (swizzled): row = nt*16+l15, global seg ks*4+quad
    // at LDS seg (ks*4+quad+l15)&7
    f32x4 sa[4];
    for (int nt = 0; nt < 4; nt++) sa[nt] = zero;
    for (int nt = 0; nt < 4; nt++)
      for (int ks = 0; ks < 2; ks++) {
        short8 kf = *reinterpret_cast<const short8*>(
            &Kbuf[buf][(nt * 16 + l15) * 64 + (((ks * 4 + quad + l15) & 7) << 3)]);
        sa[nt] = __builtin_amdgcn_mfma_f32_16x16x32_bf16(kf, qf[ks], sa[nt], 0, 0, 0);
      }

    // V frags from LDS (swizzled): row d = dt*16+l15, global seg nt*2+(quad>>1),
    // sub-offset (quad&1)*4 elems -> LDS seg (nt*2+(quad>>1)+l15)&7
    short4v vf[4][4];
    for (int dt = 0; dt < 4; dt++)
      for (int nt = 0; nt < 4; nt++)
        vf[dt][nt] = *reinterpret_cast<const short4v*>(
            &Vbuf[buf][(dt * 16 + l15) * 64 +
                       (((nt * 2 + (quad >> 1) + l15) & 7) << 3) + ((quad & 1) << 2)]);

    // p = exp2(s * 0.125*log2e + bts[idx])  (masked idx=900 -> -1e9 -> 0)
    short4v pf[4];
    for (int nt = 0; nt < 4; nt++) {
      float p[4];
      for (int r = 0; r < 4; r++) {
        float t = fmaf(sa[nt][r], SC2, bts[pkv[nt][r]]);
        p[r] = __builtin_amdgcn_exp2f(t);
      }
      denom += (p[0] + p[1]) + (p[2] + p[3]);
      short4v pk4;
      for (int r = 0; r < 4; r++) {
        bf16 tb = __float2bfloat16(p[r]);
        pk4[r] = *reinterpret_cast<short*>(&tb);
      }
      pf[nt] = pk4;
    }

    // PV: O^T[d][q] += V[d][key] * P^T[key][q]
    for (int dt = 0; dt < 4; dt++)
      for (int nt = 0; nt < 4; nt++)
        of[dt] = __builtin_amdgcn_mfma_f32_16x16x16bf16_1k(vf[dt][nt], pf[nt], of[dt], 0, 0, 0);

    if (kc < 15)
      for (int nt = 0; nt < 4; nt++) pkv[nt] = pk_n[nt];

    __syncthreads();  // staging of buf^1 complete; all reads of buf done
  }

  // cross-quad reduction of the denominator (keys split across quads)
  denom += __shfl_xor(denom, 16, 64);
  denom += __shfl_xor(denom, 32, 64);

  size_t rowi = ((size_t)z * 64 + bh) * LQ + q;
  float* orow = Opart + rowi * 64;
  for (int dt = 0; dt < 4; dt++)
    *reinterpret_cast<f32x4*>(orow + dt * 16 + quad * 4) = of[dt];
  if (quad == 0) L[rowi] = denom;
}

// ---------------- launcher ----------------

extern "C" void kernel_launch(void* const* d_in, const int* in_sizes, int n_in,
                              void* d_out, int out_size, void* d_ws, size_t ws_size,
                              hipStream_t stream) {
  const float* q = (const float*)d_in[0];
  const float* k = (const float*)d_in[1];
  const float* v = (const float*)d_in[2];
  const int* bidx = (const int*)d_in[3];
  const int* mask = (const int*)d_in[4];
  const float* Wq = (const float*)d_in[5];
  const float* bq = (const float*)d_in[6];
  const float* Wk = (const float*)d_in[7];
  const float* bk = (const float*)d_in[8];
  const float* Wv = (const float*)d_in[9];
  const float* bv = (const float*)d_in[10];
  const float* Wo = (const float*)d_in[11];
  const float* bo = (const float*)d_in[12];
  const float* btab = (const float*)d_in[13];

  char* ws = (char*)d_ws;
  bf16* qb  = (bf16*)(ws + 0);
  bf16* kb  = (bf16*)(ws + 4194304);
  bf16* vb  = (bf16*)(ws + 20971520);
  bf16* Wqb = (bf16*)(ws + 37748736);
  bf16* Wkb = (bf16*)(ws + 39845888);
  bf16* Wvb = (bf16*)(ws + 41943040);
  bf16* Wob = (bf16*)(ws + 44040192);
  bf16* Qh  = (bf16*)(ws + 46137344);
  bf16* Kh  = (bf16*)(ws + 50331648);
  bf16* Vt  = (bf16*)(ws + 67108864);
  short* pkd = (short*)(ws + 83886080);
  // btabT lives past pkd in the former Ob region (Ob deleted: combine fused
  // into gemm_o). Written by fused_cvt, read by attn9 + nothing else.
  float* btabT = (float*)(ws + 92274688);      // 57,664 B
  // Opart/L overlay qb/kb region (dead after the projection GEMMs); read by
  // attn9's consumer gemm_o directly.
  float* Opart = (float*)(ws + 0);             // 16,777,216 B (2 z-halves)
  float* L     = (float*)(ws + 16777216);      //    262,144 B
  (void)ws_size; (void)in_sizes; (void)n_in; (void)out_size;

  hipLaunchKernelGGL(fused_cvt, dim3(6657), dim3(256), 0, stream,
                     q, k, v, bidx, mask, Wq, Wk, Wv, Wo, btab,
                     qb, kb, vb, Wqb, Wkb, Wvb, Wob, pkd, btabT);

  hipLaunchKernelGGL(proj_qkv, dim3(1280), dim3(256), 0, stream,
                     kb, Wkb, bk, Kh, vb, Wvb, bv, Vt, qb, Wqb, bq, Qh);

  hipLaunchKernelGGL(attn9, dim3(BSZ * H, LQ / 128, 2), dim3(512), 0, stream,
                     Qh, Kh, Vt, pkd, btabT, Opart, L);

  hipLaunchKernelGGL(gemm_o, dim3(256), dim3(256), 0, stream,
                     Opart, Wob, bo, L, (float*)d_out);
}

// Round 11
// 297.675 us; speedup vs baseline: 1.1502x; 1.0690x over previous
//
#include <hip/hip_runtime.h>
#include <hip/hip_bf16.h>

#define H 16
#define DK 64
#define DM 1024
#define LQ 512
#define LK 2048
#define BSZ 4

typedef __hip_bfloat16 bf16;
typedef __attribute__((ext_vector_type(8))) short short8;
typedef __attribute__((ext_vector_type(4))) short short4v;
typedef __attribute__((ext_vector_type(4))) float f32x4;

#define LOG2E 1.44269504f
#define SC2 0.18033688f  // 0.125 * log2(e)

// ---------------- fused converts: q,k,v,Wq,Wk,Wv,Wo -> bf16; pack bias/mask; btabT ----------------
// (round-5 proven version: 16B/thread, 26625 blocks — the round-9/10 ILP
// rework was net-negative and is reverted)
// pkd: masked entries -> sentinel index 900 (btabT[h][900] = -1e9 -> exp2 -> 0)
// btabT: per-head 901 entries, value = (btab - 10) * log2e  (exp2-domain, shift folded)

__global__ __launch_bounds__(256) void fused_cvt(
    const float* __restrict__ q, const float* __restrict__ k, const float* __restrict__ v,
    const int* __restrict__ bidx, const int* __restrict__ msk,
    const float* __restrict__ Wq, const float* __restrict__ Wk,
    const float* __restrict__ Wv, const float* __restrict__ Wo,
    const float* __restrict__ btab,
    bf16* __restrict__ qb, bf16* __restrict__ kb, bf16* __restrict__ vb,
    bf16* __restrict__ Wqb, bf16* __restrict__ Wkb, bf16* __restrict__ Wvb,
    bf16* __restrict__ Wob, short* __restrict__ pkd, float* __restrict__ btabT) {
  const int blk = blockIdx.x, tid = threadIdx.x;
  const float* src;
  bf16* dst;
  int base;
  if (blk < 2048)       { src = q;  dst = qb;  base = blk; }
  else if (blk < 10240) { src = k;  dst = kb;  base = blk - 2048; }
  else if (blk < 18432) { src = v;  dst = vb;  base = blk - 10240; }
  else if (blk < 19456) { src = Wq; dst = Wqb; base = blk - 18432; }
  else if (blk < 20480) { src = Wk; dst = Wkb; base = blk - 19456; }
  else if (blk < 21504) { src = Wv; dst = Wvb; base = blk - 20480; }
  else if (blk < 22528) { src = Wo; dst = Wob; base = blk - 21504; }
  else if (blk < 26624) {
    int i = (blk - 22528) * 1024 + tid * 4;
    int4 a = *reinterpret_cast<const int4*>(bidx + i);
    int4 m = *reinterpret_cast<const int4*>(msk + i);
    short4 r;
    r.x = m.x ? (short)a.x : (short)900;
    r.y = m.y ? (short)a.y : (short)900;
    r.z = m.z ? (short)a.z : (short)900;
    r.w = m.w ? (short)a.w : (short)900;
    *reinterpret_cast<short4*>(pkd + i) = r;
    return;
  } else {
    // bias table: transpose + fold softmax shift (-10) + log2e, append sentinel
    for (int j = tid; j < H * 901; j += 256) {
      int hh = j / 901, i = j - hh * 901;
      btabT[j] = (i == 900) ? -1e9f : (btab[i * H + hh] - 10.0f) * LOG2E;
    }
    return;
  }
  int i = base * 1024 + tid * 4;
  float4 val = *reinterpret_cast<const float4*>(src + i);
  bf16 o0 = __float2bfloat16(val.x), o1 = __float2bfloat16(val.y);
  bf16 o2 = __float2bfloat16(val.z), o3 = __float2bfloat16(val.w);
  short4 pk;
  pk.x = *reinterpret_cast<short*>(&o0);
  pk.y = *reinterpret_cast<short*>(&o1);
  pk.z = *reinterpret_cast<short*>(&o2);
  pk.w = *reinterpret_cast<short*>(&o3);
  *reinterpret_cast<short4*>(reinterpret_cast<short*>(dst) + i) = pk;
}

// ---------------- GEMM body: C[m][n] = sum_k A[m][k]*B[n][k] + bias[n] ----------------
// Single-buffered, BK=64 K-steps (NEW round 11): halves barrier count (16 vs 32)
// and uses rotate-swizzled staging: LDS[r][seg] = G[r][(seg - r)&7] (8 segs of
// 16B per 128B row; the HW-verified attn9 pattern). Fragment reads then hit
// LDS seg (gseg + l15)&7 -> 2 lanes/bank-group = conflict-FREE (old BK=32
// linear layout was 8-way: SQ_LDS_BANK_CONFLICT 4.98M on proj).
// Frags loaded per-K-half (ks=0,1) to keep VGPR ~unchanged.
// MODE 0: write bf16 head-interleaved  dst[((b*H+h)*Lrows + l)*64 + d]
// MODE 1: d-major V dst[((b*H+h)*64 + d)*LK + key] (computed transposed in-register)
// MODE 2: write f32 row-major          dst[row*N + col]
// TM: 128 (4 waves as 2x2, 64x64 each) or 64 (4 waves as 1x4, 64x32 each)

__device__ __forceinline__ void g2lds16(const bf16* g, bf16* l) {
  __builtin_amdgcn_global_load_lds(
      (__attribute__((address_space(1))) void*)(g),
      (__attribute__((address_space(3))) void*)(l), 16, 0, 0);
}

template <int MODE, int TM>
__device__ __forceinline__ void gemm_body(bf16* __restrict__ As, bf16* __restrict__ Bs,
                                          const bf16* __restrict__ A,
                                          const bf16* __restrict__ B,
                                          const float* __restrict__ bias,
                                          void* __restrict__ out,
                                          int M, int N, int K, int Lrows,
                                          int bx, int by) {
  constexpr int NT = (TM == 128) ? 4 : 2;
  const int tid = threadIdx.x;
  const int wave = tid >> 6, lane = tid & 63;
  const int quad = lane >> 4, l15 = lane & 15;
  const int rowbase = (TM == 128) ? (wave >> 1) * 64 : 0;
  const int colbase = (TM == 128) ? (wave & 1) * 64 : wave * 32;
  const int rowA0 = bx * TM, colB0 = by * 128;
  // staging geometry: inst covers 8 rows x 8 segs; lane i -> row +(i>>3),
  // LDS seg i&7; global seg ((i&7)-(i>>3))&7  (rotate swizzle, row%8 = i>>3)
  const int sro = lane >> 3;                 // 0..7
  const int sgs = ((lane & 7) - sro) & 7;    // global segment to fetch

  f32x4 acc[4][NT];
  const f32x4 zero = {0.f, 0.f, 0.f, 0.f};
  for (int mt = 0; mt < 4; mt++)
    for (int nt = 0; nt < NT; nt++) acc[mt][nt] = zero;

  for (int k0 = 0; k0 < K; k0 += 64) {
    // stage A: TM rows x 64 cols (TM/32 insts per wave)
    for (int c = 0; c < TM / 32; ++c) {
      int r = wave * (TM / 4) + c * 8;
      g2lds16(A + (size_t)(rowA0 + r + sro) * K + k0 + sgs * 8, As + r * 64);
    }
    // stage B: 128 rows x 64 cols (4 insts per wave)
    for (int c = 0; c < 4; ++c) {
      int r = wave * 32 + c * 8;
      g2lds16(B + (size_t)(colB0 + r + sro) * K + k0 + sgs * 8, Bs + r * 64);
    }
    __syncthreads();
    // two K-halves of 32; frag for global seg g=ks*4+quad at LDS seg (g+l15)&7
    for (int ks = 0; ks < 2; ++ks) {
      short8 af[4], bfr[NT];
      for (int mt = 0; mt < 4; mt++)
        af[mt] = *reinterpret_cast<const short8*>(
            As + (rowbase + mt * 16 + l15) * 64 + (((ks * 4 + quad + l15) & 7) << 3));
      for (int nt = 0; nt < NT; nt++)
        bfr[nt] = *reinterpret_cast<const short8*>(
            Bs + (colbase + nt * 16 + l15) * 64 + (((ks * 4 + quad + l15) & 7) << 3));
      for (int mt = 0; mt < 4; mt++)
        for (int nt = 0; nt < NT; nt++) {
          if (MODE == 1)  // swapped: A-op = W rows (n), B-op = act rows (m=key)
            acc[mt][nt] = __builtin_amdgcn_mfma_f32_16x16x32_bf16(bfr[nt], af[mt], acc[mt][nt], 0, 0, 0);
          else
            acc[mt][nt] = __builtin_amdgcn_mfma_f32_16x16x32_bf16(af[mt], bfr[nt], acc[mt][nt], 0, 0, 0);
        }
    }
    __syncthreads();
  }

  const int bb = (MODE == 2) ? 0 : (rowA0 / Lrows);
  const int lb = (MODE == 2) ? rowA0 : (rowA0 - bb * Lrows);
  if (MODE == 1) {
    // D[row=quad*4+r -> n(d-col)][col=l15 -> m(key)]
    for (int mt = 0; mt < 4; mt++) {
      int key = lb + rowbase + mt * 16 + l15;
      for (int nt = 0; nt < NT; nt++) {
        f32x4 v = acc[mt][nt];
        for (int r = 0; r < 4; r++) {
          int ncol = colB0 + colbase + nt * 16 + quad * 4 + r;
          float bv = bias[ncol];
          int hh = ncol >> 6, d = ncol & 63;
          ((bf16*)out)[((size_t)((bb * H + hh) * DK + d)) * LK + key] =
              __float2bfloat16(v[r] + bv);
        }
      }
    }
    return;
  }
  for (int nt = 0; nt < NT; nt++) {
    int col = colB0 + colbase + nt * 16 + l15;
    float bv = bias[col];
    int hh = col >> 6, d = col & 63;
    for (int mt = 0; mt < 4; mt++) {
      int lrow0 = lb + rowbase + mt * 16 + quad * 4;
      f32x4 v = acc[mt][nt];
      for (int r = 0; r < 4; r++) {
        float val = v[r] + bv;
        if (MODE == 0) {
          ((bf16*)out)[(((size_t)(bb * H + hh) * Lrows + lrow0 + r) << 6) + d] = __float2bfloat16(val);
        } else {
          ((float*)out)[(size_t)(lrow0 + r) * N + col] = val;
        }
      }
    }
  }
}

// Merged Q/K/V projection: one launch, 1280 blocks (K:512, V:512, Q:256).
// XCD-chunked remap: xcd = blk&7 (HW round-robin) owns a contiguous bx-range
// with ALL by values, so each A-activation panel is fetched by exactly ONE
// XCD's L2. LDS 32KB (BK=64) -> 5 blocks/CU.
__global__ __launch_bounds__(256) void proj_qkv(
    const bf16* __restrict__ kb, const bf16* __restrict__ Wkb, const float* __restrict__ bk, bf16* __restrict__ Kh,
    const bf16* __restrict__ vb, const bf16* __restrict__ Wvb, const float* __restrict__ bv, bf16* __restrict__ Vt,
    const bf16* __restrict__ qb, const bf16* __restrict__ Wqb, const float* __restrict__ bq, bf16* __restrict__ Qh) {
  __shared__ __align__(16) bf16 As[128 * 64];
  __shared__ __align__(16) bf16 Bs[128 * 64];
  const int blk = blockIdx.x;
  if (blk < 512) {
    const int xcd = blk & 7, slot = blk >> 3;
    gemm_body<0, 128>(As, Bs, kb, Wkb, bk, (void*)Kh, 8192, 1024, 1024, LK,
                      xcd * 8 + (slot & 7), slot >> 3);
  } else if (blk < 1024) {
    const int i = blk - 512, xcd = i & 7, slot = i >> 3;
    gemm_body<1, 128>(As, Bs, vb, Wvb, bv, (void*)Vt, 8192, 1024, 1024, LK,
                      xcd * 8 + (slot & 7), slot >> 3);
  } else {
    const int i = blk - 1024, xcd = i & 7, slot = i >> 3;
    gemm_body<0, 64>(As, Bs, qb, Wqb, bq, (void*)Qh, 2048, 1024, 1024, LQ,
                     xcd * 4 + (slot & 3), slot >> 2);
  }
}

// Output projection, same XCD-chunked remap. 1-D grid of 256 blocks:
// xcd = blk&7 owns 4 bx rows x all 8 by columns (bijective over 256).
__global__ __launch_bounds__(256) void gemm_o(const bf16* __restrict__ A,
                                              const bf16* __restrict__ B,
                                              const float* __restrict__ bias,
                                              float* __restrict__ out) {
  __shared__ __align__(16) bf16 As[64 * 64];
  __shared__ __align__(16) bf16 Bs[128 * 64];
  const int blk = blockIdx.x, xcd = blk & 7, slot = blk >> 3;
  gemm_body<2, 64>(As, Bs, A, B, bias, (void*)out, 2048, 1024, 1024, LQ,
                   xcd * 4 + (slot & 3), slot >> 2);
}

// ---------------- attention v9: 8-wave blocks (128 q rows), dbuf, 1 barrier/chunk ----------------
// (round-5 proven configuration)
// grid (BSZ*H, LQ/128, 2), block 512. Block = (bh, 128 q rows, 1024 keys, 16 chunks).

__global__ __launch_bounds__(512) void attn9(const bf16* __restrict__ Qh,
                                             const bf16* __restrict__ Kh,
                                             const bf16* __restrict__ Vt,
                                             const short* __restrict__ pkm,
                                             const float* __restrict__ btabT,
                                             float* __restrict__ Opart,
                                             float* __restrict__ L) {
  __shared__ __align__(16) bf16 Kbuf[2][64 * 64];
  __shared__ __align__(16) bf16 Vbuf[2][64 * 64];
  __shared__ float bts[901];
  const int tid = threadIdx.x;
  const int wave = tid >> 6, lane = tid & 63;
  const int quad = lane >> 4, l15 = lane & 15;
  const int bh = blockIdx.x, b = bh >> 4, h = bh & 15;
  const int qt = blockIdx.y, z = blockIdx.z;
  const int key_base = z * 1024;

  for (int i = tid; i < 901; i += 512) bts[i] = btabT[h * 901 + i];

  const int q = qt * 128 + wave * 16 + l15;  // this lane's q (B-operand col)
  short8 qf[2];
  for (int ks = 0; ks < 2; ks++)
    qf[ks] = *reinterpret_cast<const short8*>(
        Qh + ((size_t)bh * LQ + q) * DK + ks * 32 + quad * 8);

  const bf16* kbase = Kh + ((size_t)bh * LK + key_base) * DK;
  const bf16* vbase = Vt + ((size_t)bh * DK) * LK + key_base;
  const short* pkrow = pkm + ((size_t)b * LQ + q) * LK + key_base;

  // staging geometry (per wave, 1 inst each for K and V):
  // lane i -> LDS row wave*8 + (i>>3), seg i&7 (lane-linear DMA);
  // row's global seg g = ((i&7) - (i>>3)) & 7   (rotate swizzle, row%8 = i>>3)
  const int srow_off = lane >> 3;                // 0..7
  const int sseg = ((lane & 7) - srow_off) & 7;  // global segment to fetch
  const int srow = wave * 8 + srow_off;          // this lane's staged row

  f32x4 of[4];
  float denom = 0.f;
  const f32x4 zero = {0.f, 0.f, 0.f, 0.f};
  for (int dt = 0; dt < 4; dt++) of[dt] = zero;

  // ---- prologue: stage chunk 0 into buf0, prefetch pk chunk 0 ----
  g2lds16(kbase + (size_t)srow * DK + sseg * 8, &Kbuf[0][(wave * 8) * 64]);
  g2lds16(vbase + (size_t)srow * LK + sseg * 8, &Vbuf[0][(wave * 8) * 64]);
  short4v pkv[4];
  for (int nt = 0; nt < 4; nt++)
    pkv[nt] = *reinterpret_cast<const short4v*>(pkrow + nt * 16 + quad * 4);

  __syncthreads();

  for (int kc = 0; kc < 16; ++kc) {
    const int buf = kc & 1;

    // stage chunk kc+1 into buf^1 (completes at the end-of-iter barrier)
    short4v pk_n[4];
    if (kc < 15) {
      const int key1 = (kc + 1) * 64;
      g2lds16(kbase + (size_t)(key1 + srow) * DK + sseg * 8,
              &Kbuf[buf ^ 1][(wave * 8) * 64]);
      g2lds16(vbase + (size_t)srow * LK + key1 + sseg * 8,
              &Vbuf[buf ^ 1][(wave * 8) * 64]);
      for (int nt = 0; nt < 4; nt++)
        pk_n[nt] = *reinterpret_cast<const short4v*>(pkrow + key1 + nt * 16 + quad * 4);
    }

    // K frags from LDS (swizzled): row = nt*16+l15, global seg ks*4+quad
    // at LDS seg (ks*4+quad+l15)&7
    f32x4 sa[4];
    for (int nt = 0; nt < 4; nt++) sa[nt] = zero;
    for (int nt = 0; nt < 4; nt++)
      for (int ks = 0; ks < 2; ks++) {
        short8 kf = *reinterpret_cast<const short8*>(
            &Kbuf[buf][(nt * 16 + l15) * 64 + (((ks * 4 + quad + l15) & 7) << 3)]);
        sa[nt] = __builtin_amdgcn_mfma_f32_16x16x32_bf16(kf, qf[ks], sa[nt], 0, 0, 0);
      }

    // V frags from LDS (swizzled): row d = dt*16+l15, global seg nt*2+(quad>>1),
    // sub-offset (quad&1)*4 elems -> LDS seg (nt*2+(quad>>1)+l15)&7
    short4v vf[4][4];
    for (int dt = 0; dt < 4; dt++)
      for (int nt = 0; nt < 4; nt++)
        vf[dt][nt] = *reinterpret_cast<const short4v*>(
            &Vbuf[buf][(dt * 16 + l15) * 64 +
                       (((nt * 2 + (quad >> 1) + l15) & 7) << 3) + ((quad & 1) << 2)]);

    // p = exp2(s * 0.125*log2e + bts[idx])  (masked idx=900 -> -1e9 -> 0)
    short4v pf[4];
    for (int nt = 0; nt < 4; nt++) {
      float p[4];
      for (int r = 0; r < 4; r++) {
        float t = fmaf(sa[nt][r], SC2, bts[pkv[nt][r]]);
        p[r] = __builtin_amdgcn_exp2f(t);
      }
      denom += (p[0] + p[1]) + (p[2] + p[3]);
      short4v pk4;
      for (int r = 0; r < 4; r++) {
        bf16 tb = __float2bfloat16(p[r]);
        pk4[r] = *reinterpret_cast<short*>(&tb);
      }
      pf[nt] = pk4;
    }

    // PV: O^T[d][q] += V[d][key] * P^T[key][q]
    for (int dt = 0; dt < 4; dt++)
      for (int nt = 0; nt < 4; nt++)
        of[dt] = __builtin_amdgcn_mfma_f32_16x16x16bf16_1k(vf[dt][nt], pf[nt], of[dt], 0, 0, 0);

    if (kc < 15)
      for (int nt = 0; nt < 4; nt++) pkv[nt] = pk_n[nt];

    __syncthreads();  // staging of buf^1 complete; all reads of buf done
  }

  // cross-quad reduction of the denominator (keys split across quads)
  denom += __shfl_xor(denom, 16, 64);
  denom += __shfl_xor(denom, 32, 64);

  size_t rowi = ((size_t)z * 64 + bh) * LQ + q;
  float* orow = Opart + rowi * 64;
  for (int dt = 0; dt < 4; dt++)
    *reinterpret_cast<f32x4*>(orow + dt * 16 + quad * 4) = of[dt];
  if (quad == 0) L[rowi] = denom;
}

// combine the two split-K halves -> bf16 Ob (plain sums; same fixed shift)
__global__ __launch_bounds__(256) void attn_combine(const float* __restrict__ Opart,
                                                    const float* __restrict__ L,
                                                    bf16* __restrict__ Ob) {
  int t = blockIdx.x * 256 + threadIdx.x;  // over 2M/4
  int g = t * 4;
  int row = g >> 6, d0 = g & 63;
  float l = L[row] + L[32768 + row];
  float4 o;
  float4 p0 = *reinterpret_cast<const float4*>(Opart + ((size_t)row << 6) + d0);
  float4 p1 = *reinterpret_cast<const float4*>(Opart + (((size_t)32768 + row) << 6) + d0);
  o.x = p0.x + p1.x; o.y = p0.y + p1.y; o.z = p0.z + p1.z; o.w = p0.w + p1.w;
  float inv = 1.f / l;
  bf16 t0 = __float2bfloat16(o.x * inv), t1 = __float2bfloat16(o.y * inv);
  bf16 t2 = __float2bfloat16(o.z * inv), t3 = __float2bfloat16(o.w * inv);
  short4 pk;
  pk.x = *reinterpret_cast<short*>(&t0);
  pk.y = *reinterpret_cast<short*>(&t1);
  pk.z = *reinterpret_cast<short*>(&t2);
  pk.w = *reinterpret_cast<short*>(&t3);
  int bh = row >> 9, qq = row & 511, b_ = bh >> 4, h = bh & 15;
  *reinterpret_cast<short4*>(Ob + ((size_t)(b_ * LQ + qq)) * DM + h * 64 + d0) = pk;
}

// ---------------- launcher ----------------

extern "C" void kernel_launch(void* const* d_in, const int* in_sizes, int n_in,
                              void* d_out, int out_size, void* d_ws, size_t ws_size,
                              hipStream_t stream) {
  const float* q = (const float*)d_in[0];
  const float* k = (const float*)d_in[1];
  const float* v = (const float*)d_in[2];
  const int* bidx = (const int*)d_in[3];
  const int* mask = (const int*)d_in[4];
  const float* Wq = (const float*)d_in[5];
  const float* bq = (const float*)d_in[6];
  const float* Wk = (const float*)d_in[7];
  const float* bk = (const float*)d_in[8];
  const float* Wv = (const float*)d_in[9];
  const float* bv = (const float*)d_in[10];
  const float* Wo = (const float*)d_in[11];
  const float* bo = (const float*)d_in[12];
  const float* btab = (const float*)d_in[13];

  char* ws = (char*)d_ws;
  bf16* qb  = (bf16*)(ws + 0);
  bf16* kb  = (bf16*)(ws + 4194304);
  bf16* vb  = (bf16*)(ws + 20971520);
  bf16* Wqb = (bf16*)(ws + 37748736);
  bf16* Wkb = (bf16*)(ws + 39845888);
  bf16* Wvb = (bf16*)(ws + 41943040);
  bf16* Wob = (bf16*)(ws + 44040192);
  bf16* Qh  = (bf16*)(ws + 46137344);
  bf16* Kh  = (bf16*)(ws + 50331648);
  bf16* Vt  = (bf16*)(ws + 67108864);
  short* pkd = (short*)(ws + 83886080);
  bf16* Ob  = (bf16*)(ws + 92274688);
  // btabT overlays the START of the Ob region: written by fused_cvt, read by
  // attn9, and only THEN overwritten by attn_combine (stream-ordered — safe).
  float* btabT = (float*)(ws + 92274688);      // 57,664 B
  // Opart/L overlay qb/kb region (dead after the projection GEMMs)
  float* Opart = (float*)(ws + 0);             // 16,777,216 B (2 z-halves)
  float* L     = (float*)(ws + 16777216);      //    262,144 B
  (void)ws_size; (void)in_sizes; (void)n_in; (void)out_size;

  hipLaunchKernelGGL(fused_cvt, dim3(26625), dim3(256), 0, stream,
                     q, k, v, bidx, mask, Wq, Wk, Wv, Wo, btab,
                     qb, kb, vb, Wqb, Wkb, Wvb, Wob, pkd, btabT);

  hipLaunchKernelGGL(proj_qkv, dim3(1280), dim3(256), 0, stream,
                     kb, Wkb, bk, Kh, vb, Wvb, bv, Vt, qb, Wqb, bq, Qh);

  hipLaunchKernelGGL(attn9, dim3(BSZ * H, LQ / 128, 2), dim3(512), 0, stream,
                     Qh, Kh, Vt, pkd, btabT, Opart, L);
  hipLaunchKernelGGL(attn_combine, dim3(2048), dim3(256), 0, stream,
                     Opart, L, Ob);

  hipLaunchKernelGGL(gemm_o, dim3(256), dim3(256), 0, stream,
                     Ob, Wob, bo, (float*)d_out);
}